// Round 1
// baseline (409.470 us; speedup 1.0000x reference)
//
#include <hip/hip_runtime.h>

// ---------------------------------------------------------------------------
// Types / helpers
// ---------------------------------------------------------------------------
typedef __bf16 bf16x8 __attribute__((ext_vector_type(8)));
typedef float  f32x4  __attribute__((ext_vector_type(4)));
typedef unsigned short ushort8 __attribute__((ext_vector_type(8)));

__device__ __forceinline__ unsigned short f2bf(float f) {
    unsigned u = __float_as_uint(f);
    u += 0x7FFFu + ((u >> 16) & 1u);   // round-to-nearest-even
    return (unsigned short)(u >> 16);
}

__device__ __forceinline__ f32x4 mfma16x16x32(bf16x8 a, bf16x8 b, f32x4 c) {
    return __builtin_amdgcn_mfma_f32_16x16x32_bf16(a, b, c, 0, 0, 0);
}

__device__ __forceinline__ bf16x8 ld8(const unsigned short* p) {
    return __builtin_bit_cast(bf16x8, *(const ushort8*)p);
}

// async global->LDS, 16B per lane. LDS dest = wave-uniform base + lane*16.
__device__ __forceinline__ void glds16(const unsigned short* g, unsigned short* l) {
    __builtin_amdgcn_global_load_lds(
        (const __attribute__((address_space(1))) void*)g,
        (__attribute__((address_space(3))) void*)l, 16, 0, 0);
}

__device__ __forceinline__ float gelu_tanh(float x) {
    const float c = 0.7978845608028654f;
    float z = c * (x + 0.044715f * x * x * x);
    float e = __expf(2.f * z);
    float th = 1.f - 2.f / (e + 1.f);   // tanh(z)
    return 0.5f * x * (1.f + th);
}

#define N_EMBD 768
#define SEQ    1024
#define NHEAD  12
#define HS     64
#define MROWS  8192           // B*T

// ---------------------------------------------------------------------------
// Transpose + cast fp32 [K,N] -> bf16 [N,K]
// ---------------------------------------------------------------------------
__global__ __launch_bounds__(256) void tcast_kernel(const float* __restrict__ in,
                                                    unsigned short* __restrict__ out,
                                                    int K, int N) {
    __shared__ float tile[32][33];
    int nb = blockIdx.x * 32, kb = blockIdx.y * 32;
    int tx = threadIdx.x, ty = threadIdx.y;   // 32 x 8
#pragma unroll
    for (int i = 0; i < 4; i++) {
        int k = kb + ty + i * 8;
        tile[ty + i * 8][tx] = in[(size_t)k * N + nb + tx];
    }
    __syncthreads();
#pragma unroll
    for (int i = 0; i < 4; i++) {
        int n = nb + ty + i * 8;
        out[(size_t)n * K + kb + tx] = f2bf(tile[tx][ty + i * 8]);
    }
}

// ---------------------------------------------------------------------------
// LayerNorm fp32 row -> bf16 row.  One 256-thread block per row (C=768).
// ---------------------------------------------------------------------------
__global__ __launch_bounds__(256) void ln_kernel(const float* __restrict__ x,
                                                 const float* __restrict__ g,
                                                 const float* __restrict__ b,
                                                 unsigned short* __restrict__ out) {
    int row = blockIdx.x;
    const float* xr = x + (size_t)row * N_EMBD;
    float v[3], s = 0.f, s2 = 0.f;
#pragma unroll
    for (int i = 0; i < 3; i++) {
        v[i] = xr[threadIdx.x + i * 256];
        s += v[i]; s2 += v[i] * v[i];
    }
#pragma unroll
    for (int m = 1; m < 64; m <<= 1) { s += __shfl_xor(s, m); s2 += __shfl_xor(s2, m); }
    __shared__ float ps[4], ps2[4];
    int wid = threadIdx.x >> 6;
    if ((threadIdx.x & 63) == 0) { ps[wid] = s; ps2[wid] = s2; }
    __syncthreads();
    s  = ps[0] + ps[1] + ps[2] + ps[3];
    s2 = ps2[0] + ps2[1] + ps2[2] + ps2[3];
    float mu  = s * (1.f / N_EMBD);
    float var = s2 * (1.f / N_EMBD) - mu * mu;
    float inv = rsqrtf(var + 1e-5f);
#pragma unroll
    for (int i = 0; i < 3; i++) {
        int c = threadIdx.x + i * 256;
        out[(size_t)row * N_EMBD + c] = f2bf((v[i] - mu) * inv * g[c] + b[c]);
    }
}

// ---------------------------------------------------------------------------
// GEMM: C[M,N] = A[M,K](bf16) @ B(bf16, stored as B^T [N,K]) + bias, epilogue.
// EPI 0: out bf16 = acc+bias ; EPI 1: out bf16 = gelu(acc+bias) ;
// EPI 2: out f32 = acc+bias+res
// 128x128 tile, BK=32, 4 waves (2x2 of 64x64), global_load_lds staging.
// ---------------------------------------------------------------------------
template <int EPI>
__global__ __launch_bounds__(256) void gemm_bt_kernel(
    const unsigned short* __restrict__ A, const unsigned short* __restrict__ BT,
    const float* __restrict__ bias, const float* __restrict__ res,
    float* __restrict__ outF, unsigned short* __restrict__ outB,
    int M, int N, int K) {
    __shared__ __attribute__((aligned(16))) unsigned short As[128 * 32];
    __shared__ __attribute__((aligned(16))) unsigned short Bs[128 * 32];
    const int m0 = blockIdx.y * 128, n0 = blockIdx.x * 128;
    const int t = threadIdx.x, lane = t & 63, wid = t >> 6;
    const int wr = wid >> 1, wc = wid & 1;

    f32x4 acc[4][4] = {};

    // staging geometry: 512 16B-chunks per 128x32 tile; thread handles chunk t and t+256
    const int c0 = t, c1 = t + 256;
    const int ar0 = c0 >> 2, ak0 = (c0 & 3) * 8;
    const int ar1 = c1 >> 2, ak1 = (c1 & 3) * 8;
    const int rrow = lane & 15, kg = (lane >> 4) * 8;

    for (int kk = 0; kk < K; kk += 32) {
        glds16(&A [(size_t)(m0 + ar0) * K + kk + ak0], &As[wid * 512]);
        glds16(&A [(size_t)(m0 + ar1) * K + kk + ak1], &As[2048 + wid * 512]);
        glds16(&BT[(size_t)(n0 + ar0) * K + kk + ak0], &Bs[wid * 512]);
        glds16(&BT[(size_t)(n0 + ar1) * K + kk + ak1], &Bs[2048 + wid * 512]);
        __syncthreads();   // compiler drains vmcnt before s_barrier
        bf16x8 af[4], bfr[4];
#pragma unroll
        for (int i = 0; i < 4; i++) af [i] = ld8(&As[(wr * 64 + i * 16 + rrow) * 32 + kg]);
#pragma unroll
        for (int j = 0; j < 4; j++) bfr[j] = ld8(&Bs[(wc * 64 + j * 16 + rrow) * 32 + kg]);
#pragma unroll
        for (int i = 0; i < 4; i++)
#pragma unroll
            for (int j = 0; j < 4; j++) acc[i][j] = mfma16x16x32(af[i], bfr[j], acc[i][j]);
        __syncthreads();
    }

    // epilogue: C/D layout col = lane&15, row = (lane>>4)*4 + r
    const int crow = (lane >> 4) * 4, ccol = lane & 15;
#pragma unroll
    for (int i = 0; i < 4; i++) {
        int gr0 = m0 + wr * 64 + i * 16 + crow;
#pragma unroll
        for (int j = 0; j < 4; j++) {
            int gc = n0 + wc * 64 + j * 16 + ccol;
            float bv = bias[gc];
#pragma unroll
            for (int r = 0; r < 4; r++) {
                int gr = gr0 + r;
                float v = acc[i][j][r] + bv;
                if constexpr (EPI == 1) v = gelu_tanh(v);
                if constexpr (EPI == 2) {
                    outF[(size_t)gr * N + gc] = v + res[(size_t)gr * N + gc];
                } else {
                    outB[(size_t)gr * N + gc] = f2bf(v);
                }
            }
        }
    }
}

// ---------------------------------------------------------------------------
// Causal flash attention. qkv bf16 [8192, 2304] (q|k|v blocks of 768).
// Grid (16 q-tiles, 96 b*h). Block 256 = 4 waves; wave owns 16 q-rows.
// KV tile = 32 rows. Out: yb bf16 [8192, 768].
// ---------------------------------------------------------------------------
__global__ __launch_bounds__(256) void attn_kernel(const unsigned short* __restrict__ qkv,
                                                   unsigned short* __restrict__ yb) {
    const int qt = blockIdx.x, bh = blockIdx.y;
    const int b = bh / NHEAD, h = bh % NHEAD;
    const int q0 = qt * 64;
    const int t = threadIdx.x, lane = t & 63, wid = t >> 6;
    const int q0w = q0 + wid * 16;
    const int rrow = lane & 15, kg8 = (lane >> 4) * 8;

    __shared__ __attribute__((aligned(16))) unsigned short Ks[32 * 80];  // [32][80] pad
    __shared__ __attribute__((aligned(16))) unsigned short Vt[64 * 40];  // [64][40] pad (transposed V)
    __shared__ __attribute__((aligned(16))) unsigned short Ps[4][16 * 40];

    // Q fragments (A-operand): row = lane&15, d = dh*32 + kg8..+7
    bf16x8 qf[2];
    {
        size_t base = ((size_t)(b * SEQ + q0w + rrow)) * 2304 + h * HS;
        qf[0] = ld8(&qkv[base + kg8]);
        qf[1] = ld8(&qkv[base + 32 + kg8]);
    }

    f32x4 yacc[4] = {};
    float mrow[4], lrow[4];
#pragma unroll
    for (int r = 0; r < 4; r++) { mrow[r] = -1e30f; lrow[r] = 0.f; }

    const int nt = 2 * qt + 2;
    for (int tt = 0; tt < nt; tt++) {
        const int kv0 = tt * 32;
        // ---- stage K [32][64] (padded 80) and V transposed [64][40] ----
        {
            int row = t >> 3, dc = (t & 7) * 8;
            size_t gk = ((size_t)(b * SEQ + kv0 + row)) * 2304 + 768 + h * HS + dc;
            ushort8 k8 = *(const ushort8*)&qkv[gk];
            *(ushort8*)&Ks[row * 80 + dc] = k8;
            size_t gv = ((size_t)(b * SEQ + kv0 + row)) * 2304 + 1536 + h * HS + dc;
            ushort8 v8 = *(const ushort8*)&qkv[gv];
#pragma unroll
            for (int i = 0; i < 8; i++) Vt[(dc + i) * 40 + row] = v8[i];
        }
        __syncthreads();

        if (kv0 <= q0w + 15) {
            // ---- S = Q K^T (two 16x16 tiles) ----
            f32x4 s[2];
#pragma unroll
            for (int ct = 0; ct < 2; ct++) {
                f32x4 z = {};
                bf16x8 k0 = ld8(&Ks[(ct * 16 + rrow) * 80 + kg8]);
                bf16x8 k1 = ld8(&Ks[(ct * 16 + rrow) * 80 + 32 + kg8]);
                z = mfma16x16x32(qf[0], k0, z);
                z = mfma16x16x32(qf[1], k1, z);
                s[ct] = z;
            }
            // ---- scale + causal mask + row max ----
            float pmax[4];
#pragma unroll
            for (int r = 0; r < 4; r++) pmax[r] = -1e30f;
            const int qrb = q0w + (lane >> 4) * 4;
#pragma unroll
            for (int ct = 0; ct < 2; ct++) {
                int j = kv0 + ct * 16 + rrow;
#pragma unroll
                for (int r = 0; r < 4; r++) {
                    float v = s[ct][r] * 0.125f;
                    if (j > qrb + r) v = -1e30f;
                    s[ct][r] = v;
                    pmax[r] = fmaxf(pmax[r], v);
                }
            }
#pragma unroll
            for (int m = 1; m < 16; m <<= 1)
#pragma unroll
                for (int r = 0; r < 4; r++) pmax[r] = fmaxf(pmax[r], __shfl_xor(pmax[r], m));
            // ---- online softmax update ----
            float alpha[4];
#pragma unroll
            for (int r = 0; r < 4; r++) {
                float mn = fmaxf(mrow[r], pmax[r]);
                alpha[r] = __expf(mrow[r] - mn);
                mrow[r] = mn;
            }
            float rsum[4] = {0.f, 0.f, 0.f, 0.f};
#pragma unroll
            for (int ct = 0; ct < 2; ct++)
#pragma unroll
                for (int r = 0; r < 4; r++) {
                    float p = __expf(s[ct][r] - mrow[r]);
                    s[ct][r] = p;
                    rsum[r] += p;
                }
#pragma unroll
            for (int m = 1; m < 16; m <<= 1)
#pragma unroll
                for (int r = 0; r < 4; r++) rsum[r] += __shfl_xor(rsum[r], m);
#pragma unroll
            for (int r = 0; r < 4; r++) lrow[r] = lrow[r] * alpha[r] + rsum[r];
#pragma unroll
            for (int dt = 0; dt < 4; dt++)
#pragma unroll
                for (int r = 0; r < 4; r++) yacc[dt][r] *= alpha[r];
            // ---- P -> LDS (C layout) then re-read as A fragments ----
            unsigned short* P = &Ps[wid][0];
#pragma unroll
            for (int ct = 0; ct < 2; ct++)
#pragma unroll
                for (int r = 0; r < 4; r++)
                    P[((lane >> 4) * 4 + r) * 40 + ct * 16 + rrow] = f2bf(s[ct][r]);
            asm volatile("s_waitcnt lgkmcnt(0)" ::: "memory");
            bf16x8 pa = ld8(&P[rrow * 40 + kg8]);
#pragma unroll
            for (int dt = 0; dt < 4; dt++) {
                bf16x8 vb = ld8(&Vt[(dt * 16 + rrow) * 40 + kg8]);
                yacc[dt] = mfma16x16x32(pa, vb, yacc[dt]);
            }
        }
        __syncthreads();
    }

    // ---- write out: row q = (lane>>4)*4+r, col d = dt*16 + (lane&15) ----
    const int qrow = (lane >> 4) * 4;
#pragma unroll
    for (int dt = 0; dt < 4; dt++)
#pragma unroll
        for (int r = 0; r < 4; r++) {
            float v = yacc[dt][r] / lrow[r];
            yb[((size_t)(b * SEQ + q0w + qrow + r)) * N_EMBD + h * HS + dt * 16 + rrow] = f2bf(v);
        }
}

// ---------------------------------------------------------------------------
// Orchestration
// ---------------------------------------------------------------------------
extern "C" void kernel_launch(void* const* d_in, const int* in_sizes, int n_in,
                              void* d_out, int out_size, void* d_ws, size_t ws_size,
                              hipStream_t stream) {
    const float* x        = (const float*)d_in[0];
    const float* ln1_g    = (const float*)d_in[1];
    const float* ln1_b    = (const float*)d_in[2];
    const float* w_attn   = (const float*)d_in[3];
    const float* b_attn   = (const float*)d_in[4];
    const float* w_proj   = (const float*)d_in[5];
    const float* b_proj   = (const float*)d_in[6];
    const float* ln2_g    = (const float*)d_in[7];
    const float* ln2_b    = (const float*)d_in[8];
    const float* w_fc     = (const float*)d_in[9];
    const float* b_fc     = (const float*)d_in[10];
    const float* w_fcp    = (const float*)d_in[11];
    const float* b_fcp    = (const float*)d_in[12];
    float* out = (float*)d_out;

    // workspace carve (ushort elements)
    unsigned short* ws = (unsigned short*)d_ws;
    unsigned short* wT_attn = ws;                          // 2304*768
    unsigned short* wT_proj = wT_attn + 2304 * 768;        // 768*768
    unsigned short* wT_fc   = wT_proj + 768 * 768;         // 3072*768
    unsigned short* wT_fcp  = wT_fc   + 3072 * 768;        // 768*3072
    unsigned short* xb      = wT_fcp  + 768 * 3072;        // 8192*768 (ln1 out, later ln2 out)
    unsigned short* qkv     = xb      + (size_t)MROWS * 768;   // 8192*2304
    unsigned short* yb      = qkv     + (size_t)MROWS * 2304;  // 8192*768 (attn out)
    unsigned short* act     = qkv;    // 8192*3072 overlays qkv+yb (both dead by then)
    float* x2 = (float*)(yb + (size_t)MROWS * 768);        // 8192*768 fp32

    dim3 tb(32, 8);
    // weight transposes (fp32 [K,N] -> bf16 [N,K])
    tcast_kernel<<<dim3(2304 / 32, 768 / 32), tb, 0, stream>>>(w_attn, wT_attn, 768, 2304);
    tcast_kernel<<<dim3(768 / 32, 768 / 32),  tb, 0, stream>>>(w_proj, wT_proj, 768, 768);
    tcast_kernel<<<dim3(3072 / 32, 768 / 32), tb, 0, stream>>>(w_fc,   wT_fc,   768, 3072);
    tcast_kernel<<<dim3(768 / 32, 3072 / 32), tb, 0, stream>>>(w_fcp,  wT_fcp,  3072, 768);

    // ln1
    ln_kernel<<<MROWS, 256, 0, stream>>>(x, ln1_g, ln1_b, xb);
    // qkv = ln1(x) @ w_attn + b_attn
    gemm_bt_kernel<0><<<dim3(2304 / 128, MROWS / 128), 256, 0, stream>>>(
        xb, wT_attn, b_attn, nullptr, nullptr, qkv, MROWS, 2304, 768);
    // attention
    attn_kernel<<<dim3(16, 8 * NHEAD), 256, 0, stream>>>(qkv, yb);
    // x2 = attn_y @ w_proj + b_proj + x
    gemm_bt_kernel<2><<<dim3(768 / 128, MROWS / 128), 256, 0, stream>>>(
        yb, wT_proj, b_proj, x, x2, nullptr, MROWS, 768, 768);
    // ln2
    ln_kernel<<<MROWS, 256, 0, stream>>>(x2, ln2_g, ln2_b, xb);
    // act = gelu(h2 @ w_fc + b_fc)
    gemm_bt_kernel<1><<<dim3(3072 / 128, MROWS / 128), 256, 0, stream>>>(
        xb, wT_fc, b_fc, nullptr, nullptr, act, MROWS, 3072, 768);
    // out = act @ w_fc_proj + b_fc_proj + x2
    gemm_bt_kernel<2><<<dim3(768 / 128, MROWS / 128), 256, 0, stream>>>(
        act, wT_fcp, b_fcp, x2, out, nullptr, MROWS, 768, 3072);
}

// Round 3
// 323.427 us; speedup vs baseline: 1.2660x; 1.2660x over previous
//
#include <hip/hip_runtime.h>

// ---------------------------------------------------------------------------
// Types / helpers
// ---------------------------------------------------------------------------
typedef __bf16 bf16x8 __attribute__((ext_vector_type(8)));
typedef float  f32x4  __attribute__((ext_vector_type(4)));
typedef unsigned short ushort8 __attribute__((ext_vector_type(8)));

__device__ __forceinline__ unsigned short f2bf(float f) {
    unsigned u = __float_as_uint(f);
    u += 0x7FFFu + ((u >> 16) & 1u);   // round-to-nearest-even
    return (unsigned short)(u >> 16);
}

__device__ __forceinline__ f32x4 mfma16x16x32(bf16x8 a, bf16x8 b, f32x4 c) {
    return __builtin_amdgcn_mfma_f32_16x16x32_bf16(a, b, c, 0, 0, 0);
}

__device__ __forceinline__ bf16x8 ld8(const unsigned short* p) {
    return __builtin_bit_cast(bf16x8, *(const ushort8*)p);
}

// async global->LDS, 16B per lane. LDS dest = wave-uniform base + lane*16.
__device__ __forceinline__ void glds16(const unsigned short* g, unsigned short* l) {
    __builtin_amdgcn_global_load_lds(
        (const __attribute__((address_space(1))) void*)g,
        (__attribute__((address_space(3))) void*)l, 16, 0, 0);
}

__device__ __forceinline__ float gelu_tanh(float x) {
    const float c = 0.7978845608028654f;
    float z = c * (x + 0.044715f * x * x * x);
    float e = __expf(2.f * z);
    float th = 1.f - 2.f / (e + 1.f);   // tanh(z)
    return 0.5f * x * (1.f + th);
}

#define N_EMBD 768
#define SEQ    1024
#define NHEAD  12
#define HS     64
#define MROWS  8192           // B*T

// ---------------------------------------------------------------------------
// Transpose + cast fp32 [K,N] -> bf16 [N,K]
// ---------------------------------------------------------------------------
__global__ __launch_bounds__(256) void tcast_kernel(const float* __restrict__ in,
                                                    unsigned short* __restrict__ out,
                                                    int K, int N) {
    __shared__ float tile[32][33];
    int nb = blockIdx.x * 32, kb = blockIdx.y * 32;
    int tx = threadIdx.x, ty = threadIdx.y;   // 32 x 8
#pragma unroll
    for (int i = 0; i < 4; i++) {
        int k = kb + ty + i * 8;
        tile[ty + i * 8][tx] = in[(size_t)k * N + nb + tx];
    }
    __syncthreads();
#pragma unroll
    for (int i = 0; i < 4; i++) {
        int n = nb + ty + i * 8;
        out[(size_t)n * K + kb + tx] = f2bf(tile[tx][ty + i * 8]);
    }
}

// ---------------------------------------------------------------------------
// LayerNorm fp32 row -> bf16 row.  One 256-thread block per row (C=768).
// ---------------------------------------------------------------------------
__global__ __launch_bounds__(256) void ln_kernel(const float* __restrict__ x,
                                                 const float* __restrict__ g,
                                                 const float* __restrict__ b,
                                                 unsigned short* __restrict__ out) {
    int row = blockIdx.x;
    const float* xr = x + (size_t)row * N_EMBD;
    float v[3], s = 0.f, s2 = 0.f;
#pragma unroll
    for (int i = 0; i < 3; i++) {
        v[i] = xr[threadIdx.x + i * 256];
        s += v[i]; s2 += v[i] * v[i];
    }
#pragma unroll
    for (int m = 1; m < 64; m <<= 1) { s += __shfl_xor(s, m); s2 += __shfl_xor(s2, m); }
    __shared__ float ps[4], ps2[4];
    int wid = threadIdx.x >> 6;
    if ((threadIdx.x & 63) == 0) { ps[wid] = s; ps2[wid] = s2; }
    __syncthreads();
    s  = ps[0] + ps[1] + ps[2] + ps[3];
    s2 = ps2[0] + ps2[1] + ps2[2] + ps2[3];
    float mu  = s * (1.f / N_EMBD);
    float var = s2 * (1.f / N_EMBD) - mu * mu;
    float inv = rsqrtf(var + 1e-5f);
#pragma unroll
    for (int i = 0; i < 3; i++) {
        int c = threadIdx.x + i * 256;
        out[(size_t)row * N_EMBD + c] = f2bf((v[i] - mu) * inv * g[c] + b[c]);
    }
}

// ---------------------------------------------------------------------------
// GEMM: C[M,N] = A[M,K](bf16) @ B(bf16, stored as B^T [N,K]) + bias, epilogue.
// EPI 0: out bf16 = acc+bias ; EPI 1: out bf16 = gelu(acc+bias) ;
// EPI 2: out f32 = acc+bias+res
// Tile (WM*32) x 128, BK=32, 4 waves (2x2), global_load_lds staging.
// WM=4 -> 128x128; WM=2 -> 64x128 (for small-N GEMMs, more blocks).
// ---------------------------------------------------------------------------
template <int EPI, int WM>
__global__ __launch_bounds__(256) void gemm_bt_kernel(
    const unsigned short* __restrict__ A, const unsigned short* __restrict__ BT,
    const float* __restrict__ bias, const float* __restrict__ res,
    float* __restrict__ outF, unsigned short* __restrict__ outB,
    int M, int N, int K) {
    constexpr int BM = WM * 32;
    __shared__ __attribute__((aligned(16))) unsigned short As[BM * 32];
    __shared__ __attribute__((aligned(16))) unsigned short Bs[128 * 32];
    const int m0 = blockIdx.y * BM, n0 = blockIdx.x * 128;
    const int t = threadIdx.x, lane = t & 63, wid = t >> 6;
    const int wr = wid >> 1, wc = wid & 1;

    f32x4 acc[WM][4] = {};

    const int ar = t >> 2, ak = (t & 3) * 8;
    const int rrow = lane & 15, kg = (lane >> 4) * 8;

    for (int kk = 0; kk < K; kk += 32) {
        glds16(&A[(size_t)(m0 + ar) * K + kk + ak], &As[wid * 512]);
        if constexpr (WM == 4)
            glds16(&A[(size_t)(m0 + 64 + ar) * K + kk + ak], &As[2048 + wid * 512]);
        glds16(&BT[(size_t)(n0 + ar) * K + kk + ak], &Bs[wid * 512]);
        glds16(&BT[(size_t)(n0 + 64 + ar) * K + kk + ak], &Bs[2048 + wid * 512]);
        __syncthreads();   // drains vmcnt before s_barrier
        bf16x8 af[WM], bfr[4];
#pragma unroll
        for (int i = 0; i < WM; i++) af[i] = ld8(&As[(wr * (WM * 16) + i * 16 + rrow) * 32 + kg]);
#pragma unroll
        for (int j = 0; j < 4; j++) bfr[j] = ld8(&Bs[(wc * 64 + j * 16 + rrow) * 32 + kg]);
#pragma unroll
        for (int i = 0; i < WM; i++)
#pragma unroll
            for (int j = 0; j < 4; j++) acc[i][j] = mfma16x16x32(af[i], bfr[j], acc[i][j]);
        __syncthreads();
    }

    // epilogue: C/D layout col = lane&15, row = (lane>>4)*4 + r
    const int crow = (lane >> 4) * 4, ccol = lane & 15;
#pragma unroll
    for (int i = 0; i < WM; i++) {
        int gr0 = m0 + wr * (WM * 16) + i * 16 + crow;
#pragma unroll
        for (int j = 0; j < 4; j++) {
            int gc = n0 + wc * 64 + j * 16 + ccol;
            float bv = bias[gc];
#pragma unroll
            for (int r = 0; r < 4; r++) {
                int gr = gr0 + r;
                float v = acc[i][j][r] + bv;
                if constexpr (EPI == 1) v = gelu_tanh(v);
                if constexpr (EPI == 2) {
                    outF[(size_t)gr * N + gc] = v + res[(size_t)gr * N + gc];
                } else {
                    outB[(size_t)gr * N + gc] = f2bf(v);
                }
            }
        }
    }
}

// ---------------------------------------------------------------------------
// Causal flash attention v2. qkv bf16 [8192, 2304] (q|k|v blocks of 768).
// Grid (8, 96): block p handles q-tiles p and 15-p (load-balanced: 17 KV64
// tiles each). Block 256 = 4 waves; wave owns 16 q-rows of each tile.
// K staged via global_load_lds w/ pre-swizzled source into Ks[64][64];
// V staged d-major (coalesced u16 loads) into Vt[64][88] (conflict-free).
// ---------------------------------------------------------------------------
__device__ __forceinline__ void attn_tile(
    const unsigned short* Ks, const unsigned short* Vt, unsigned short* P,
    const bf16x8* qf, f32x4* yacc, float* mrow, float* lrow,
    int q0w, int kv0, bool masked, int lane)
{
    const int rrow = lane & 15, g = lane >> 4, kg8 = g * 8;
    // ---- S = Q K^T (4 col tiles of 16, k=64 in 2 slices) ----
    f32x4 s[4];
#pragma unroll
    for (int ct = 0; ct < 4; ct++) {
        const int j = ct * 16 + rrow;
        const unsigned short* kr = &Ks[j * 64];
        f32x4 z = {};
        z = mfma16x16x32(qf[0], ld8(&kr[((g    ) ^ (j & 7)) * 8]), z);
        z = mfma16x16x32(qf[1], ld8(&kr[((g + 4) ^ (j & 7)) * 8]), z);
        s[ct] = z;
    }
    // ---- scale + causal mask + row max ----
    float pmax[4] = {-1e30f, -1e30f, -1e30f, -1e30f};
    const int qrb = q0w + g * 4;
#pragma unroll
    for (int ct = 0; ct < 4; ct++) {
        const int j = kv0 + ct * 16 + rrow;
#pragma unroll
        for (int r = 0; r < 4; r++) {
            float v = s[ct][r] * 0.125f;
            if (masked && j > qrb + r) v = -1e30f;
            s[ct][r] = v;
            pmax[r] = fmaxf(pmax[r], v);
        }
    }
#pragma unroll
    for (int m = 1; m < 16; m <<= 1)
#pragma unroll
        for (int r = 0; r < 4; r++) pmax[r] = fmaxf(pmax[r], __shfl_xor(pmax[r], m));
    // ---- online softmax ----
    float alpha[4];
#pragma unroll
    for (int r = 0; r < 4; r++) {
        float mn = fmaxf(mrow[r], pmax[r]);
        alpha[r] = __expf(mrow[r] - mn);
        mrow[r] = mn;
    }
    float rsum[4] = {0.f, 0.f, 0.f, 0.f};
#pragma unroll
    for (int ct = 0; ct < 4; ct++)
#pragma unroll
        for (int r = 0; r < 4; r++) {
            float pv = __expf(s[ct][r] - mrow[r]);
            s[ct][r] = pv;
            rsum[r] += pv;
        }
#pragma unroll
    for (int m = 1; m < 16; m <<= 1)
#pragma unroll
        for (int r = 0; r < 4; r++) rsum[r] += __shfl_xor(rsum[r], m);
#pragma unroll
    for (int r = 0; r < 4; r++) lrow[r] = lrow[r] * alpha[r] + rsum[r];
#pragma unroll
    for (int dt = 0; dt < 4; dt++)
#pragma unroll
        for (int r = 0; r < 4; r++) yacc[dt][r] *= alpha[r];
    // ---- P -> LDS (XOR-swizzled by q) then reread as A fragments ----
#pragma unroll
    for (int ct = 0; ct < 4; ct++)
#pragma unroll
        for (int r = 0; r < 4; r++) {
            const int q = g * 4 + r;
            P[q * 80 + ((ct * 16 + rrow) ^ ((q & 7) << 3))] = f2bf(s[ct][r]);
        }
    asm volatile("s_waitcnt lgkmcnt(0)" ::: "memory");
    const int sw = (rrow & 7) << 3;
    bf16x8 pa0 = ld8(&P[rrow * 80 + ((kg8     ) ^ sw)]);
    bf16x8 pa1 = ld8(&P[rrow * 80 + ((kg8 + 32) ^ sw)]);
#pragma unroll
    for (int dt = 0; dt < 4; dt++) {
        const unsigned short* vr = &Vt[(dt * 16 + rrow) * 88];
        yacc[dt] = mfma16x16x32(pa0, ld8(&vr[kg8     ]), yacc[dt]);
        yacc[dt] = mfma16x16x32(pa1, ld8(&vr[kg8 + 32]), yacc[dt]);
    }
}

__global__ __launch_bounds__(256) void attn_kernel(const unsigned short* __restrict__ qkv,
                                                   unsigned short* __restrict__ yb) {
    const int p = blockIdx.x;                  // 0..7
    const int bh = blockIdx.y;
    const int b = bh / NHEAD, h = bh % NHEAD;
    const int t = threadIdx.x, lane = t & 63, wid = t >> 6;
    const int q0A = p * 64 + wid * 16, q0B = (15 - p) * 64 + wid * 16;
    const int ntA = p + 1, ntB = 16 - p;
    const int rrow = lane & 15, g = lane >> 4, kg8 = g * 8;

    __shared__ __attribute__((aligned(16))) unsigned short Ks[64 * 64];
    __shared__ __attribute__((aligned(16))) unsigned short Vt[64 * 88];
    __shared__ __attribute__((aligned(16))) unsigned short Ps[4][16 * 80];

    // Q fragments (A-operand): row = lane&15, k = (lane>>4)*8 + j
    bf16x8 qfA[2], qfB[2];
    {
        size_t baseA = ((size_t)(b * SEQ + q0A + rrow)) * 2304 + h * HS;
        qfA[0] = ld8(&qkv[baseA + kg8]);
        qfA[1] = ld8(&qkv[baseA + 32 + kg8]);
        size_t baseB = ((size_t)(b * SEQ + q0B + rrow)) * 2304 + h * HS;
        qfB[0] = ld8(&qkv[baseB + kg8]);
        qfB[1] = ld8(&qkv[baseB + 32 + kg8]);
    }

    f32x4 yA[4] = {}, yB[4] = {};
    float mA[4], lA[4], mB[4], lB[4];
#pragma unroll
    for (int r = 0; r < 4; r++) { mA[r] = mB[r] = -1e30f; lA[r] = lB[r] = 0.f; }

    // K staging geometry: 512 16B chunks; thread owns chunks t and t+256.
    // chunk n: row = n>>3, stored col-chunk c' = n&7 holds source chunk c'^(row&7)
    const int kr0 = t >> 3, kr1 = kr0 + 32;
    const int kc0 = ((t & 7) ^ (kr0 & 7)) * 8;
    const int kc1 = ((t & 7) ^ (kr1 & 7)) * 8;     // == kc0 (32 ≡ 0 mod 8) but keep explicit
    // V staging: thread owns column d = t&63, kv rows wid*16 .. +15
    const int vd = t & 63, vk = wid * 16;

    for (int tt = 0; tt < ntB; tt++) {
        const int kv0 = tt * 64;
        __syncthreads();   // previous tile's LDS reads complete
        // K -> Ks[64][64] via async DMA, source pre-swizzled.
        // chunks 0..255 at ushort 0; chunks 256..511 at ushort 2048 (=256*8).
        glds16(&qkv[((size_t)(b * SEQ + kv0 + kr0)) * 2304 + 768 + h * HS + kc0], &Ks[wid * 512]);
        glds16(&qkv[((size_t)(b * SEQ + kv0 + kr1)) * 2304 + 768 + h * HS + kc1], &Ks[2048 + wid * 512]);
        // V -> Vt[d][kv] (transposed) via d-major coalesced loads
        ushort8 vlo, vhi;
#pragma unroll
        for (int i = 0; i < 8; i++)
            vlo[i] = qkv[((size_t)(b * SEQ + kv0 + vk + i)) * 2304 + 1536 + h * HS + vd];
#pragma unroll
        for (int i = 0; i < 8; i++)
            vhi[i] = qkv[((size_t)(b * SEQ + kv0 + vk + 8 + i)) * 2304 + 1536 + h * HS + vd];
        *(ushort8*)&Vt[vd * 88 + vk] = vlo;
        *(ushort8*)&Vt[vd * 88 + vk + 8] = vhi;
        __syncthreads();   // staging visible (drains vmcnt + lgkmcnt)

        attn_tile(Ks, Vt, &Ps[wid][0], qfB, yB, mB, lB, q0B, kv0, tt == ntB - 1, lane);
        if (tt < ntA)
            attn_tile(Ks, Vt, &Ps[wid][0], qfA, yA, mA, lA, q0A, kv0, tt == ntA - 1, lane);
    }

    // ---- write out both q-tiles ----
#pragma unroll
    for (int dt = 0; dt < 4; dt++)
#pragma unroll
        for (int r = 0; r < 4; r++) {
            int col = h * HS + dt * 16 + rrow;
            yb[((size_t)(b * SEQ + q0B + g * 4 + r)) * N_EMBD + col] = f2bf(yB[dt][r] / lB[r]);
            yb[((size_t)(b * SEQ + q0A + g * 4 + r)) * N_EMBD + col] = f2bf(yA[dt][r] / lA[r]);
        }
}

// ---------------------------------------------------------------------------
// Orchestration
// ---------------------------------------------------------------------------
extern "C" void kernel_launch(void* const* d_in, const int* in_sizes, int n_in,
                              void* d_out, int out_size, void* d_ws, size_t ws_size,
                              hipStream_t stream) {
    const float* x        = (const float*)d_in[0];
    const float* ln1_g    = (const float*)d_in[1];
    const float* ln1_b    = (const float*)d_in[2];
    const float* w_attn   = (const float*)d_in[3];
    const float* b_attn   = (const float*)d_in[4];
    const float* w_proj   = (const float*)d_in[5];
    const float* b_proj   = (const float*)d_in[6];
    const float* ln2_g    = (const float*)d_in[7];
    const float* ln2_b    = (const float*)d_in[8];
    const float* w_fc     = (const float*)d_in[9];
    const float* b_fc     = (const float*)d_in[10];
    const float* w_fcp    = (const float*)d_in[11];
    const float* b_fcp    = (const float*)d_in[12];
    float* out = (float*)d_out;

    // workspace carve (ushort elements)
    unsigned short* ws = (unsigned short*)d_ws;
    unsigned short* wT_attn = ws;                          // 2304*768
    unsigned short* wT_proj = wT_attn + 2304 * 768;        // 768*768
    unsigned short* wT_fc   = wT_proj + 768 * 768;         // 3072*768
    unsigned short* wT_fcp  = wT_fc   + 3072 * 768;        // 768*3072
    unsigned short* xb      = wT_fcp  + 768 * 3072;        // 8192*768 (ln1 out, later ln2 out)
    unsigned short* qkv     = xb      + (size_t)MROWS * 768;   // 8192*2304
    unsigned short* yb      = qkv     + (size_t)MROWS * 2304;  // 8192*768 (attn out)
    unsigned short* act     = qkv;    // 8192*3072 overlays qkv+yb (both dead by then)
    float* x2 = (float*)(yb + (size_t)MROWS * 768);        // 8192*768 fp32

    dim3 tb(32, 8);
    // weight transposes (fp32 [K,N] -> bf16 [N,K])
    tcast_kernel<<<dim3(2304 / 32, 768 / 32), tb, 0, stream>>>(w_attn, wT_attn, 768, 2304);
    tcast_kernel<<<dim3(768 / 32, 768 / 32),  tb, 0, stream>>>(w_proj, wT_proj, 768, 768);
    tcast_kernel<<<dim3(3072 / 32, 768 / 32), tb, 0, stream>>>(w_fc,   wT_fc,   768, 3072);
    tcast_kernel<<<dim3(768 / 32, 3072 / 32), tb, 0, stream>>>(w_fcp,  wT_fcp,  3072, 768);

    // ln1
    ln_kernel<<<MROWS, 256, 0, stream>>>(x, ln1_g, ln1_b, xb);
    // qkv = ln1(x) @ w_attn + b_attn
    gemm_bt_kernel<0, 4><<<dim3(2304 / 128, MROWS / 128), 256, 0, stream>>>(
        xb, wT_attn, b_attn, nullptr, nullptr, qkv, MROWS, 2304, 768);
    // attention (load-balanced paired q-tiles)
    attn_kernel<<<dim3(8, 8 * NHEAD), 256, 0, stream>>>(qkv, yb);
    // x2 = attn_y @ w_proj + b_proj + x     (N=768: 64x128 tile -> 768 blocks)
    gemm_bt_kernel<2, 2><<<dim3(768 / 128, MROWS / 64), 256, 0, stream>>>(
        yb, wT_proj, b_proj, x, x2, nullptr, MROWS, 768, 768);
    // ln2
    ln_kernel<<<MROWS, 256, 0, stream>>>(x2, ln2_g, ln2_b, xb);
    // act = gelu(h2 @ w_fc + b_fc)
    gemm_bt_kernel<1, 4><<<dim3(3072 / 128, MROWS / 128), 256, 0, stream>>>(
        xb, wT_fc, b_fc, nullptr, nullptr, act, MROWS, 3072, 768);
    // out = act @ w_fc_proj + b_fc_proj + x2
    gemm_bt_kernel<2, 2><<<dim3(768 / 128, MROWS / 64), 256, 0, stream>>>(
        act, wT_fcp, b_fcp, x2, out, nullptr, MROWS, 768, 3072);
}

// Round 4
// 314.946 us; speedup vs baseline: 1.3001x; 1.0269x over previous
//
#include <hip/hip_runtime.h>

// ---------------------------------------------------------------------------
// Types / helpers
// ---------------------------------------------------------------------------
typedef __bf16 bf16x8 __attribute__((ext_vector_type(8)));
typedef float  f32x4  __attribute__((ext_vector_type(4)));
typedef unsigned short ushort8 __attribute__((ext_vector_type(8)));

__device__ __forceinline__ unsigned short f2bf(float f) {
    unsigned u = __float_as_uint(f);
    u += 0x7FFFu + ((u >> 16) & 1u);   // round-to-nearest-even
    return (unsigned short)(u >> 16);
}

__device__ __forceinline__ f32x4 mfma16x16x32(bf16x8 a, bf16x8 b, f32x4 c) {
    return __builtin_amdgcn_mfma_f32_16x16x32_bf16(a, b, c, 0, 0, 0);
}

__device__ __forceinline__ bf16x8 ld8(const unsigned short* p) {
    return __builtin_bit_cast(bf16x8, *(const ushort8*)p);
}

// raw v_exp_f32 (exp2). Input <= ~0..11.5 or very negative; flush-to-zero ok.
__device__ __forceinline__ float exp2_fast(float x) {
    float r; asm("v_exp_f32 %0, %1" : "=v"(r) : "v"(x)); return r;
}

// async global->LDS, 16B per lane. LDS dest = wave-uniform base + lane*16.
__device__ __forceinline__ void glds16(const unsigned short* g, unsigned short* l) {
    __builtin_amdgcn_global_load_lds(
        (const __attribute__((address_space(1))) void*)g,
        (__attribute__((address_space(3))) void*)l, 16, 0, 0);
}

__device__ __forceinline__ float gelu_tanh(float x) {
    const float c = 0.7978845608028654f;
    float z = c * (x + 0.044715f * x * x * x);
    float e = __expf(2.f * z);
    float th = 1.f - 2.f / (e + 1.f);   // tanh(z)
    return 0.5f * x * (1.f + th);
}

#define N_EMBD 768
#define SEQ    1024
#define NHEAD  12
#define HS     64
#define MROWS  8192           // B*T

// ---------------------------------------------------------------------------
// Transpose + cast fp32 [K,N] -> bf16 [N,K]
// ---------------------------------------------------------------------------
__global__ __launch_bounds__(256) void tcast_kernel(const float* __restrict__ in,
                                                    unsigned short* __restrict__ out,
                                                    int K, int N) {
    __shared__ float tile[32][33];
    int nb = blockIdx.x * 32, kb = blockIdx.y * 32;
    int tx = threadIdx.x, ty = threadIdx.y;   // 32 x 8
#pragma unroll
    for (int i = 0; i < 4; i++) {
        int k = kb + ty + i * 8;
        tile[ty + i * 8][tx] = in[(size_t)k * N + nb + tx];
    }
    __syncthreads();
#pragma unroll
    for (int i = 0; i < 4; i++) {
        int n = nb + ty + i * 8;
        out[(size_t)n * K + kb + tx] = f2bf(tile[tx][ty + i * 8]);
    }
}

// ---------------------------------------------------------------------------
// LayerNorm fp32 row -> bf16 row.  One 256-thread block per row (C=768).
// ---------------------------------------------------------------------------
__global__ __launch_bounds__(256) void ln_kernel(const float* __restrict__ x,
                                                 const float* __restrict__ g,
                                                 const float* __restrict__ b,
                                                 unsigned short* __restrict__ out) {
    int row = blockIdx.x;
    const float* xr = x + (size_t)row * N_EMBD;
    float v[3], s = 0.f, s2 = 0.f;
#pragma unroll
    for (int i = 0; i < 3; i++) {
        v[i] = xr[threadIdx.x + i * 256];
        s += v[i]; s2 += v[i] * v[i];
    }
#pragma unroll
    for (int m = 1; m < 64; m <<= 1) { s += __shfl_xor(s, m); s2 += __shfl_xor(s2, m); }
    __shared__ float ps[4], ps2[4];
    int wid = threadIdx.x >> 6;
    if ((threadIdx.x & 63) == 0) { ps[wid] = s; ps2[wid] = s2; }
    __syncthreads();
    s  = ps[0] + ps[1] + ps[2] + ps[3];
    s2 = ps2[0] + ps2[1] + ps2[2] + ps2[3];
    float mu  = s * (1.f / N_EMBD);
    float var = s2 * (1.f / N_EMBD) - mu * mu;
    float inv = rsqrtf(var + 1e-5f);
#pragma unroll
    for (int i = 0; i < 3; i++) {
        int c = threadIdx.x + i * 256;
        out[(size_t)row * N_EMBD + c] = f2bf((v[i] - mu) * inv * g[c] + b[c]);
    }
}

// ---------------------------------------------------------------------------
// GEMM: C[M,N] = A[M,K](bf16) @ B(bf16, stored as B^T [N,K]) + bias, epilogue.
// EPI 0: out bf16 = acc+bias ; EPI 1: out bf16 = gelu(acc+bias) ;
// EPI 2: out f32 = acc+bias+res
// Tile (WM*32) x 128, BK=64, 4 waves (2x2), global_load_lds staging with
// XOR chunk swizzle (source pre-swizzled; same involution on ds_read).
// WM=4 -> 128x128; WM=2 -> 64x128 (for small-N GEMMs, more blocks).
// ---------------------------------------------------------------------------
template <int EPI, int WM>
__global__ __launch_bounds__(256) void gemm_bt_kernel(
    const unsigned short* __restrict__ A, const unsigned short* __restrict__ BT,
    const float* __restrict__ bias, const float* __restrict__ res,
    float* __restrict__ outF, unsigned short* __restrict__ outB,
    int M, int N, int K) {
    constexpr int BM = WM * 32;
    __shared__ __attribute__((aligned(16))) unsigned short As[BM * 64];
    __shared__ __attribute__((aligned(16))) unsigned short Bs[128 * 64];
    const int m0 = blockIdx.y * BM, n0 = blockIdx.x * 128;
    const int t = threadIdx.x, lane = t & 63, wid = t >> 6;
    const int wr = wid >> 1, wc = wid & 1;

    f32x4 acc[WM][4] = {};

    const int rrow = lane & 15, g = lane >> 4;
    const int swz8 = (rrow & 7) << 3;       // XOR swizzle on read (ushort units)

    // staging: chunk n = i*256 + t; row = n>>3; stored col-chunk (n&7) holds
    // source col-chunk (n&7)^(row&7). Dest base per instr = i*2048 + wid*512.
    const int srow = t >> 3;
    const int scol = ((t & 7) ^ (srow & 7)) * 8;

    for (int kk = 0; kk < K; kk += 64) {
#pragma unroll
        for (int i = 0; i < WM; i++)
            glds16(&A[(size_t)(m0 + i * 32 + srow) * K + kk + scol], &As[i * 2048 + wid * 512]);
#pragma unroll
        for (int i = 0; i < 4; i++)
            glds16(&BT[(size_t)(n0 + i * 32 + srow) * K + kk + scol], &Bs[i * 2048 + wid * 512]);
        __syncthreads();   // drains vmcnt before s_barrier
#pragma unroll
        for (int s = 0; s < 2; s++) {
            bf16x8 af[WM], bfr[4];
#pragma unroll
            for (int i = 0; i < WM; i++) {
                int row = wr * (WM * 16) + i * 16 + rrow;
                af[i] = ld8(&As[row * 64 + ((((s << 2) | g) << 3) ^ swz8)]);
            }
#pragma unroll
            for (int j = 0; j < 4; j++) {
                int row = wc * 64 + j * 16 + rrow;
                bfr[j] = ld8(&Bs[row * 64 + ((((s << 2) | g) << 3) ^ swz8)]);
            }
#pragma unroll
            for (int i = 0; i < WM; i++)
#pragma unroll
                for (int j = 0; j < 4; j++) acc[i][j] = mfma16x16x32(af[i], bfr[j], acc[i][j]);
        }
        __syncthreads();
    }

    // epilogue: C/D layout col = lane&15, row = (lane>>4)*4 + r
    const int crow = g * 4, ccol = rrow;
#pragma unroll
    for (int i = 0; i < WM; i++) {
        int gr0 = m0 + wr * (WM * 16) + i * 16 + crow;
#pragma unroll
        for (int j = 0; j < 4; j++) {
            int gc = n0 + wc * 64 + j * 16 + ccol;
            float bv = bias[gc];
#pragma unroll
            for (int r = 0; r < 4; r++) {
                int gr = gr0 + r;
                float v = acc[i][j][r] + bv;
                if constexpr (EPI == 1) v = gelu_tanh(v);
                if constexpr (EPI == 2) {
                    outF[(size_t)gr * N + gc] = v + res[(size_t)gr * N + gc];
                } else {
                    outB[(size_t)gr * N + gc] = f2bf(v);
                }
            }
        }
    }
}

// ---------------------------------------------------------------------------
// Causal flash attention. qkv bf16 [8192, 2304] (q|k|v blocks of 768).
// Grid (8, 96): block p handles q-tiles p and 15-p (17 KV64 tiles each).
// Softmax in log2 domain (raw v_exp_f32), defer-max rescale (T13),
// row-sum via MFMA against ones (replaces shuffle-reduce).
// ---------------------------------------------------------------------------
#define SCALE_LOG2E 0.18033688011112042f   // 0.125 * log2(e)
#define DEFER_TH    11.5f                  // ~= 8 nats in log2 units

__device__ __forceinline__ void attn_tile(
    const unsigned short* Ks, const unsigned short* Vt, unsigned short* P,
    const bf16x8* qf, f32x4* yacc, float* mrow, float* lrow,
    int q0w, int kv0, bool masked, int lane)
{
    const int rrow = lane & 15, g = lane >> 4, kg8 = g * 8;
    // ---- S = Q K^T (4 col tiles of 16, k=64 in 2 slices) ----
    f32x4 s[4];
#pragma unroll
    for (int ct = 0; ct < 4; ct++) {
        const int j = ct * 16 + rrow;
        const unsigned short* kr = &Ks[j * 64];
        f32x4 z = {};
        z = mfma16x16x32(qf[0], ld8(&kr[((g    ) ^ (j & 7)) * 8]), z);
        z = mfma16x16x32(qf[1], ld8(&kr[((g + 4) ^ (j & 7)) * 8]), z);
        s[ct] = z;
    }
    // ---- scale (log2 domain) + causal mask + row max ----
    float pmax[4] = {-1e30f, -1e30f, -1e30f, -1e30f};
    const int qrb = q0w + g * 4;
#pragma unroll
    for (int ct = 0; ct < 4; ct++) {
        const int j = kv0 + ct * 16 + rrow;
#pragma unroll
        for (int r = 0; r < 4; r++) {
            float v = s[ct][r] * SCALE_LOG2E;
            if (masked && j > qrb + r) v = -1e30f;
            s[ct][r] = v;
            pmax[r] = fmaxf(pmax[r], v);
        }
    }
#pragma unroll
    for (int m = 1; m < 16; m <<= 1)
#pragma unroll
        for (int r = 0; r < 4; r++) pmax[r] = fmaxf(pmax[r], __shfl_xor(pmax[r], m));
    // ---- defer-max online rescale ----
    bool need = false;
#pragma unroll
    for (int r = 0; r < 4; r++) need |= (pmax[r] > mrow[r] + DEFER_TH);
    if (__any(need)) {
#pragma unroll
        for (int r = 0; r < 4; r++) {
            float mn = fmaxf(mrow[r], pmax[r]);
            float a = exp2_fast(mrow[r] - mn);
            mrow[r] = mn;
            lrow[r] *= a;
#pragma unroll
            for (int dt = 0; dt < 4; dt++) yacc[dt][r] *= a;
        }
    }
    // ---- P = exp2(s - m) -> LDS (XOR-swizzled by q) ----
#pragma unroll
    for (int ct = 0; ct < 4; ct++)
#pragma unroll
        for (int r = 0; r < 4; r++) {
            const int q = g * 4 + r;
            P[q * 80 + ((ct * 16 + rrow) ^ ((q & 7) << 3))] = f2bf(exp2_fast(s[ct][r] - mrow[r]));
        }
    asm volatile("s_waitcnt lgkmcnt(0)" ::: "memory");
    const int sw = (rrow & 7) << 3;
    bf16x8 pa0 = ld8(&P[rrow * 80 + ((kg8     ) ^ sw)]);
    bf16x8 pa1 = ld8(&P[rrow * 80 + ((kg8 + 32) ^ sw)]);
    // ---- row-sum via MFMA against ones; PV ----
    const bf16x8 vones = __builtin_bit_cast(bf16x8,
        (ushort8){0x3F80, 0x3F80, 0x3F80, 0x3F80, 0x3F80, 0x3F80, 0x3F80, 0x3F80});
    f32x4 ss = {};
    ss = mfma16x16x32(pa0, vones, ss);
    ss = mfma16x16x32(pa1, vones, ss);
#pragma unroll
    for (int r = 0; r < 4; r++) lrow[r] += ss[r];
#pragma unroll
    for (int dt = 0; dt < 4; dt++) {
        const unsigned short* vr = &Vt[(dt * 16 + rrow) * 88];
        yacc[dt] = mfma16x16x32(pa0, ld8(&vr[kg8     ]), yacc[dt]);
        yacc[dt] = mfma16x16x32(pa1, ld8(&vr[kg8 + 32]), yacc[dt]);
    }
}

__global__ __launch_bounds__(256) void attn_kernel(const unsigned short* __restrict__ qkv,
                                                   unsigned short* __restrict__ yb) {
    const int p = blockIdx.x;                  // 0..7
    const int bh = blockIdx.y;
    const int b = bh / NHEAD, h = bh % NHEAD;
    const int t = threadIdx.x, lane = t & 63, wid = t >> 6;
    const int q0A = p * 64 + wid * 16, q0B = (15 - p) * 64 + wid * 16;
    const int ntA = p + 1, ntB = 16 - p;
    const int rrow = lane & 15, g = lane >> 4, kg8 = g * 8;

    __shared__ __attribute__((aligned(16))) unsigned short Ks[64 * 64];
    __shared__ __attribute__((aligned(16))) unsigned short Vt[64 * 88];
    __shared__ __attribute__((aligned(16))) unsigned short Ps[4][16 * 80];

    // Q fragments (A-operand): row = lane&15, k = (lane>>4)*8 + j
    bf16x8 qfA[2], qfB[2];
    {
        size_t baseA = ((size_t)(b * SEQ + q0A + rrow)) * 2304 + h * HS;
        qfA[0] = ld8(&qkv[baseA + kg8]);
        qfA[1] = ld8(&qkv[baseA + 32 + kg8]);
        size_t baseB = ((size_t)(b * SEQ + q0B + rrow)) * 2304 + h * HS;
        qfB[0] = ld8(&qkv[baseB + kg8]);
        qfB[1] = ld8(&qkv[baseB + 32 + kg8]);
    }

    f32x4 yA[4] = {}, yB[4] = {};
    float mA[4], lA[4], mB[4], lB[4];
#pragma unroll
    for (int r = 0; r < 4; r++) { mA[r] = mB[r] = -1e30f; lA[r] = lB[r] = 0.f; }

    // K staging geometry: 512 16B chunks; thread owns chunks t and t+256.
    const int kr0 = t >> 3, kr1 = kr0 + 32;
    const int kc0 = ((t & 7) ^ (kr0 & 7)) * 8;
    const int kc1 = ((t & 7) ^ (kr1 & 7)) * 8;
    // V staging: thread owns column d = t&63, kv rows wid*16 .. +15
    const int vd = t & 63, vk = wid * 16;

    for (int tt = 0; tt < ntB; tt++) {
        const int kv0 = tt * 64;
        __syncthreads();   // previous tile's LDS reads complete
        // K -> Ks[64][64] via async DMA, source pre-swizzled.
        glds16(&qkv[((size_t)(b * SEQ + kv0 + kr0)) * 2304 + 768 + h * HS + kc0], &Ks[wid * 512]);
        glds16(&qkv[((size_t)(b * SEQ + kv0 + kr1)) * 2304 + 768 + h * HS + kc1], &Ks[2048 + wid * 512]);
        // V -> Vt[d][kv] (transposed) via d-major coalesced loads
        ushort8 vlo, vhi;
#pragma unroll
        for (int i = 0; i < 8; i++)
            vlo[i] = qkv[((size_t)(b * SEQ + kv0 + vk + i)) * 2304 + 1536 + h * HS + vd];
#pragma unroll
        for (int i = 0; i < 8; i++)
            vhi[i] = qkv[((size_t)(b * SEQ + kv0 + vk + 8 + i)) * 2304 + 1536 + h * HS + vd];
        *(ushort8*)&Vt[vd * 88 + vk] = vlo;
        *(ushort8*)&Vt[vd * 88 + vk + 8] = vhi;
        __syncthreads();   // staging visible (drains vmcnt + lgkmcnt)

        attn_tile(Ks, Vt, &Ps[wid][0], qfB, yB, mB, lB, q0B, kv0, tt == ntB - 1, lane);
        if (tt < ntA)
            attn_tile(Ks, Vt, &Ps[wid][0], qfA, yA, mA, lA, q0A, kv0, tt == ntA - 1, lane);
    }

    // ---- write out both q-tiles ----
#pragma unroll
    for (int dt = 0; dt < 4; dt++)
#pragma unroll
        for (int r = 0; r < 4; r++) {
            int col = h * HS + dt * 16 + rrow;
            yb[((size_t)(b * SEQ + q0B + g * 4 + r)) * N_EMBD + col] = f2bf(yB[dt][r] / lB[r]);
            yb[((size_t)(b * SEQ + q0A + g * 4 + r)) * N_EMBD + col] = f2bf(yA[dt][r] / lA[r]);
        }
}

// ---------------------------------------------------------------------------
// Orchestration
// ---------------------------------------------------------------------------
extern "C" void kernel_launch(void* const* d_in, const int* in_sizes, int n_in,
                              void* d_out, int out_size, void* d_ws, size_t ws_size,
                              hipStream_t stream) {
    const float* x        = (const float*)d_in[0];
    const float* ln1_g    = (const float*)d_in[1];
    const float* ln1_b    = (const float*)d_in[2];
    const float* w_attn   = (const float*)d_in[3];
    const float* b_attn   = (const float*)d_in[4];
    const float* w_proj   = (const float*)d_in[5];
    const float* b_proj   = (const float*)d_in[6];
    const float* ln2_g    = (const float*)d_in[7];
    const float* ln2_b    = (const float*)d_in[8];
    const float* w_fc     = (const float*)d_in[9];
    const float* b_fc     = (const float*)d_in[10];
    const float* w_fcp    = (const float*)d_in[11];
    const float* b_fcp    = (const float*)d_in[12];
    float* out = (float*)d_out;

    // workspace carve (ushort elements)
    unsigned short* ws = (unsigned short*)d_ws;
    unsigned short* wT_attn = ws;                          // 2304*768
    unsigned short* wT_proj = wT_attn + 2304 * 768;        // 768*768
    unsigned short* wT_fc   = wT_proj + 768 * 768;         // 3072*768
    unsigned short* wT_fcp  = wT_fc   + 3072 * 768;        // 768*3072
    unsigned short* xb      = wT_fcp  + 768 * 3072;        // 8192*768 (ln1 out, later ln2 out)
    unsigned short* qkv     = xb      + (size_t)MROWS * 768;   // 8192*2304
    unsigned short* yb      = qkv     + (size_t)MROWS * 2304;  // 8192*768 (attn out)
    unsigned short* act     = qkv;    // 8192*3072 overlays qkv+yb (both dead by then)
    float* x2 = (float*)(yb + (size_t)MROWS * 768);        // 8192*768 fp32

    dim3 tb(32, 8);
    // weight transposes (fp32 [K,N] -> bf16 [N,K])
    tcast_kernel<<<dim3(2304 / 32, 768 / 32), tb, 0, stream>>>(w_attn, wT_attn, 768, 2304);
    tcast_kernel<<<dim3(768 / 32, 768 / 32),  tb, 0, stream>>>(w_proj, wT_proj, 768, 768);
    tcast_kernel<<<dim3(3072 / 32, 768 / 32), tb, 0, stream>>>(w_fc,   wT_fc,   768, 3072);
    tcast_kernel<<<dim3(768 / 32, 3072 / 32), tb, 0, stream>>>(w_fcp,  wT_fcp,  3072, 768);

    // ln1
    ln_kernel<<<MROWS, 256, 0, stream>>>(x, ln1_g, ln1_b, xb);
    // qkv = ln1(x) @ w_attn + b_attn
    gemm_bt_kernel<0, 4><<<dim3(2304 / 128, MROWS / 128), 256, 0, stream>>>(
        xb, wT_attn, b_attn, nullptr, nullptr, qkv, MROWS, 2304, 768);
    // attention (load-balanced paired q-tiles)
    attn_kernel<<<dim3(8, 8 * NHEAD), 256, 0, stream>>>(qkv, yb);
    // x2 = attn_y @ w_proj + b_proj + x     (N=768: 64x128 tile -> 768 blocks)
    gemm_bt_kernel<2, 2><<<dim3(768 / 128, MROWS / 64), 256, 0, stream>>>(
        yb, wT_proj, b_proj, x, x2, nullptr, MROWS, 768, 768);
    // ln2
    ln_kernel<<<MROWS, 256, 0, stream>>>(x2, ln2_g, ln2_b, xb);
    // act = gelu(h2 @ w_fc + b_fc)
    gemm_bt_kernel<1, 4><<<dim3(3072 / 128, MROWS / 128), 256, 0, stream>>>(
        xb, wT_fc, b_fc, nullptr, nullptr, act, MROWS, 3072, 768);
    // out = act @ w_fc_proj + b_fc_proj + x2
    gemm_bt_kernel<2, 2><<<dim3(768 / 128, MROWS / 64), 256, 0, stream>>>(
        act, wT_fcp, b_fcp, x2, out, nullptr, MROWS, 768, 3072);
}

// Round 5
// 294.030 us; speedup vs baseline: 1.3926x; 1.0711x over previous
//
#include <hip/hip_runtime.h>

// ---------------------------------------------------------------------------
// Types / helpers
// ---------------------------------------------------------------------------
typedef __bf16 bf16x8 __attribute__((ext_vector_type(8)));
typedef float  f32x4  __attribute__((ext_vector_type(4)));
typedef unsigned short ushort8 __attribute__((ext_vector_type(8)));

__device__ __forceinline__ unsigned short f2bf(float f) {
    unsigned u = __float_as_uint(f);
    u += 0x7FFFu + ((u >> 16) & 1u);   // round-to-nearest-even
    return (unsigned short)(u >> 16);
}

__device__ __forceinline__ f32x4 mfma16x16x32(bf16x8 a, bf16x8 b, f32x4 c) {
    return __builtin_amdgcn_mfma_f32_16x16x32_bf16(a, b, c, 0, 0, 0);
}

__device__ __forceinline__ bf16x8 ld8(const unsigned short* p) {
    return __builtin_bit_cast(bf16x8, *(const ushort8*)p);
}

// raw v_exp_f32 (exp2). Input <= ~12 or very negative; flush-to-zero ok.
__device__ __forceinline__ float exp2_fast(float x) {
    float r; asm("v_exp_f32 %0, %1" : "=v"(r) : "v"(x)); return r;
}

// async global->LDS, 16B per lane. LDS dest = wave-uniform base + lane*16.
__device__ __forceinline__ void glds16(const unsigned short* g, unsigned short* l) {
    __builtin_amdgcn_global_load_lds(
        (const __attribute__((address_space(1))) void*)g,
        (__attribute__((address_space(3))) void*)l, 16, 0, 0);
}

__device__ __forceinline__ float gelu_tanh(float x) {
    const float c = 0.7978845608028654f;
    float z = c * (x + 0.044715f * x * x * x);
    float e = __expf(2.f * z);
    float th = 1.f - 2.f / (e + 1.f);   // tanh(z)
    return 0.5f * x * (1.f + th);
}

#define N_EMBD 768
#define SEQ    1024
#define NHEAD  12
#define HS     64
#define MROWS  8192           // B*T

// ---------------------------------------------------------------------------
// Transpose + cast fp32 [K,N] -> bf16 [N,K]
// ---------------------------------------------------------------------------
__global__ __launch_bounds__(256) void tcast_kernel(const float* __restrict__ in,
                                                    unsigned short* __restrict__ out,
                                                    int K, int N) {
    __shared__ float tile[32][33];
    int nb = blockIdx.x * 32, kb = blockIdx.y * 32;
    int tx = threadIdx.x, ty = threadIdx.y;   // 32 x 8
#pragma unroll
    for (int i = 0; i < 4; i++) {
        int k = kb + ty + i * 8;
        tile[ty + i * 8][tx] = in[(size_t)k * N + nb + tx];
    }
    __syncthreads();
#pragma unroll
    for (int i = 0; i < 4; i++) {
        int n = nb + ty + i * 8;
        out[(size_t)n * K + kb + tx] = f2bf(tile[tx][ty + i * 8]);
    }
}

// ---------------------------------------------------------------------------
// LayerNorm fp32 row -> bf16 row.  One 256-thread block per row (C=768).
// ---------------------------------------------------------------------------
__global__ __launch_bounds__(256) void ln_kernel(const float* __restrict__ x,
                                                 const float* __restrict__ g,
                                                 const float* __restrict__ b,
                                                 unsigned short* __restrict__ out) {
    int row = blockIdx.x;
    const float* xr = x + (size_t)row * N_EMBD;
    float v[3], s = 0.f, s2 = 0.f;
#pragma unroll
    for (int i = 0; i < 3; i++) {
        v[i] = xr[threadIdx.x + i * 256];
        s += v[i]; s2 += v[i] * v[i];
    }
#pragma unroll
    for (int m = 1; m < 64; m <<= 1) { s += __shfl_xor(s, m); s2 += __shfl_xor(s2, m); }
    __shared__ float ps[4], ps2[4];
    int wid = threadIdx.x >> 6;
    if ((threadIdx.x & 63) == 0) { ps[wid] = s; ps2[wid] = s2; }
    __syncthreads();
    s  = ps[0] + ps[1] + ps[2] + ps[3];
    s2 = ps2[0] + ps2[1] + ps2[2] + ps2[3];
    float mu  = s * (1.f / N_EMBD);
    float var = s2 * (1.f / N_EMBD) - mu * mu;
    float inv = rsqrtf(var + 1e-5f);
#pragma unroll
    for (int i = 0; i < 3; i++) {
        int c = threadIdx.x + i * 256;
        out[(size_t)row * N_EMBD + c] = f2bf((v[i] - mu) * inv * g[c] + b[c]);
    }
}

// ---------------------------------------------------------------------------
// GEMM: C[M,N] = A[M,K](bf16) @ B(bf16, stored as B^T [N,K]) + bias, epilogue.
// EPI 0: out bf16 = acc+bias ; EPI 1: out bf16 = gelu(acc+bias) ;
// EPI 2: out f32 = acc+bias+res
// Tile (WM*32) x 128, BK=64, 4 waves (2x2), global_load_lds staging with
// XOR chunk swizzle. Bijective XCD-aware block remap (grid % 8 == 0).
// ---------------------------------------------------------------------------
template <int EPI, int WM>
__global__ __launch_bounds__(256) void gemm_bt_kernel(
    const unsigned short* __restrict__ A, const unsigned short* __restrict__ BT,
    const float* __restrict__ bias, const float* __restrict__ res,
    float* __restrict__ outF, unsigned short* __restrict__ outB,
    int M, int N, int K) {
    constexpr int BM = WM * 32;
    __shared__ __attribute__((aligned(16))) unsigned short As[BM * 64];
    __shared__ __attribute__((aligned(16))) unsigned short Bs[128 * 64];
    // XCD-aware remap: dispatch slot s runs on XCD s%8; give each XCD a
    // contiguous logical chunk so its L2 sees neighboring tiles.
    const int gx = gridDim.x;
    const int slot = blockIdx.y * gx + blockIdx.x;
    const int chunk = (gx * gridDim.y) >> 3;
    const int logical = (slot & 7) * chunk + (slot >> 3);
    const int m0 = (logical / gx) * BM, n0 = (logical % gx) * 128;
    const int t = threadIdx.x, lane = t & 63, wid = t >> 6;
    const int wr = wid >> 1, wc = wid & 1;

    f32x4 acc[WM][4] = {};

    const int rrow = lane & 15, g = lane >> 4;
    const int swz8 = (rrow & 7) << 3;       // XOR swizzle on read (ushort units)

    // staging: chunk n = i*256 + t; row = n>>3; stored col-chunk (n&7) holds
    // source col-chunk (n&7)^(row&7). Dest base per instr = i*2048 + wid*512.
    const int srow = t >> 3;
    const int scol = ((t & 7) ^ (srow & 7)) * 8;

    for (int kk = 0; kk < K; kk += 64) {
#pragma unroll
        for (int i = 0; i < WM; i++)
            glds16(&A[(size_t)(m0 + i * 32 + srow) * K + kk + scol], &As[i * 2048 + wid * 512]);
#pragma unroll
        for (int i = 0; i < 4; i++)
            glds16(&BT[(size_t)(n0 + i * 32 + srow) * K + kk + scol], &Bs[i * 2048 + wid * 512]);
        __syncthreads();   // drains vmcnt before s_barrier
#pragma unroll
        for (int s = 0; s < 2; s++) {
            bf16x8 af[WM], bfr[4];
#pragma unroll
            for (int i = 0; i < WM; i++) {
                int row = wr * (WM * 16) + i * 16 + rrow;
                af[i] = ld8(&As[row * 64 + ((((s << 2) | g) << 3) ^ swz8)]);
            }
#pragma unroll
            for (int j = 0; j < 4; j++) {
                int row = wc * 64 + j * 16 + rrow;
                bfr[j] = ld8(&Bs[row * 64 + ((((s << 2) | g) << 3) ^ swz8)]);
            }
#pragma unroll
            for (int i = 0; i < WM; i++)
#pragma unroll
                for (int j = 0; j < 4; j++) acc[i][j] = mfma16x16x32(af[i], bfr[j], acc[i][j]);
        }
        __syncthreads();
    }

    // epilogue: C/D layout col = lane&15, row = (lane>>4)*4 + r
    const int crow = g * 4, ccol = rrow;
#pragma unroll
    for (int i = 0; i < WM; i++) {
        int gr0 = m0 + wr * (WM * 16) + i * 16 + crow;
#pragma unroll
        for (int j = 0; j < 4; j++) {
            int gc = n0 + wc * 64 + j * 16 + ccol;
            float bv = bias[gc];
#pragma unroll
            for (int r = 0; r < 4; r++) {
                int gr = gr0 + r;
                float v = acc[i][j][r] + bv;
                if constexpr (EPI == 1) v = gelu_tanh(v);
                if constexpr (EPI == 2) {
                    outF[(size_t)gr * N + gc] = v + res[(size_t)gr * N + gc];
                } else {
                    outB[(size_t)gr * N + gc] = f2bf(v);
                }
            }
        }
    }
}

// ---------------------------------------------------------------------------
// Causal flash attention. qkv bf16 [8192, 2304] (q|k|v blocks of 768).
// Logical grid 768 = 8 pairings x 96 bh, XCD-remapped so one bh's 8 blocks
// share an XCD L2 (KV panel 256KB). 512 threads = 8 waves: waves 0-3 own
// q-tile 15-p, waves 4-7 own q-tile p; K/V staging shared, one attn_tile
// per wave per staged KV64 tile (half the serial chain of the 4-wave ver).
// Softmax: log2-domain, defer-max (T13), row-sum via MFMA vs ones.
// ---------------------------------------------------------------------------
#define SCALE_LOG2E 0.18033688011112042f   // 0.125 * log2(e)
#define DEFER_TH    11.5f                  // ~= 8 nats in log2 units

__device__ __forceinline__ void attn_tile(
    const unsigned short* Ks, const unsigned short* Vt, unsigned short* P,
    const bf16x8* qf, f32x4* yacc, float* mrow, float* lrow,
    int q0w, int kv0, bool masked, int lane)
{
    const int rrow = lane & 15, g = lane >> 4, kg8 = g * 8;
    // ---- S = Q K^T (4 col tiles of 16, k=64 in 2 slices) ----
    f32x4 s[4];
#pragma unroll
    for (int ct = 0; ct < 4; ct++) {
        const int j = ct * 16 + rrow;
        const unsigned short* kr = &Ks[j * 64];
        f32x4 z = {};
        z = mfma16x16x32(qf[0], ld8(&kr[((g    ) ^ (j & 7)) * 8]), z);
        z = mfma16x16x32(qf[1], ld8(&kr[((g + 4) ^ (j & 7)) * 8]), z);
        s[ct] = z;
    }
    // ---- scale (log2 domain) + causal mask + row max ----
    float pmax[4] = {-1e30f, -1e30f, -1e30f, -1e30f};
    const int qrb = q0w + g * 4;
#pragma unroll
    for (int ct = 0; ct < 4; ct++) {
        const int j = kv0 + ct * 16 + rrow;
#pragma unroll
        for (int r = 0; r < 4; r++) {
            float v = s[ct][r] * SCALE_LOG2E;
            if (masked && j > qrb + r) v = -1e30f;
            s[ct][r] = v;
            pmax[r] = fmaxf(pmax[r], v);
        }
    }
#pragma unroll
    for (int m = 1; m < 16; m <<= 1)
#pragma unroll
        for (int r = 0; r < 4; r++) pmax[r] = fmaxf(pmax[r], __shfl_xor(pmax[r], m));
    // ---- defer-max online rescale ----
    bool need = false;
#pragma unroll
    for (int r = 0; r < 4; r++) need |= (pmax[r] > mrow[r] + DEFER_TH);
    if (__any(need)) {
#pragma unroll
        for (int r = 0; r < 4; r++) {
            float mn = fmaxf(mrow[r], pmax[r]);
            float a = exp2_fast(mrow[r] - mn);
            mrow[r] = mn;
            lrow[r] *= a;
#pragma unroll
            for (int dt = 0; dt < 4; dt++) yacc[dt][r] *= a;
        }
    }
    // ---- P = exp2(s - m) -> LDS (XOR-swizzled by q) ----
#pragma unroll
    for (int ct = 0; ct < 4; ct++)
#pragma unroll
        for (int r = 0; r < 4; r++) {
            const int q = g * 4 + r;
            P[q * 80 + ((ct * 16 + rrow) ^ ((q & 7) << 3))] = f2bf(exp2_fast(s[ct][r] - mrow[r]));
        }
    asm volatile("s_waitcnt lgkmcnt(0)" ::: "memory");
    const int sw = (rrow & 7) << 3;
    bf16x8 pa0 = ld8(&P[rrow * 80 + ((kg8     ) ^ sw)]);
    bf16x8 pa1 = ld8(&P[rrow * 80 + ((kg8 + 32) ^ sw)]);
    // ---- row-sum via MFMA against ones; PV ----
    const bf16x8 vones = __builtin_bit_cast(bf16x8,
        (ushort8){0x3F80, 0x3F80, 0x3F80, 0x3F80, 0x3F80, 0x3F80, 0x3F80, 0x3F80});
    f32x4 ss = {};
    ss = mfma16x16x32(pa0, vones, ss);
    ss = mfma16x16x32(pa1, vones, ss);
#pragma unroll
    for (int r = 0; r < 4; r++) lrow[r] += ss[r];
#pragma unroll
    for (int dt = 0; dt < 4; dt++) {
        const unsigned short* vr = &Vt[(dt * 16 + rrow) * 88];
        yacc[dt] = mfma16x16x32(pa0, ld8(&vr[kg8     ]), yacc[dt]);
        yacc[dt] = mfma16x16x32(pa1, ld8(&vr[kg8 + 32]), yacc[dt]);
    }
}

__global__ __launch_bounds__(512, 6) void attn_kernel(const unsigned short* __restrict__ qkv,
                                                      unsigned short* __restrict__ yb) {
    // XCD remap over logical grid 768 (p fastest, then bh)
    const int slot = blockIdx.y * 8 + blockIdx.x;
    const int logical = (slot & 7) * 96 + (slot >> 3);
    const int p = logical & 7;                 // 0..7
    const int bh = logical >> 3;               // 0..95
    const int b = bh / NHEAD, h = bh % NHEAD;
    const int t = threadIdx.x, lane = t & 63, wid = t >> 6;   // wid 0..7
    const int half = wid >> 2, w4 = wid & 3;
    const int qt = half ? p : (15 - p);
    const int ntSelf = half ? (p + 1) : (16 - p);
    const int ntMax = 16 - p;                  // >= ntSelf always
    const int q0w = qt * 64 + w4 * 16;
    const int rrow = lane & 15, g = lane >> 4, kg8 = g * 8;

    __shared__ __attribute__((aligned(16))) unsigned short Ks[64 * 64];
    __shared__ __attribute__((aligned(16))) unsigned short Vt[64 * 88];
    __shared__ __attribute__((aligned(16))) unsigned short Ps[8][16 * 80];

    // Q fragments (A-operand): row = lane&15, k = (lane>>4)*8 + j
    bf16x8 qf[2];
    {
        size_t base = ((size_t)(b * SEQ + q0w + rrow)) * 2304 + h * HS;
        qf[0] = ld8(&qkv[base + kg8]);
        qf[1] = ld8(&qkv[base + 32 + kg8]);
    }

    f32x4 y[4] = {};
    float mrow[4], lrow[4];
#pragma unroll
    for (int r = 0; r < 4; r++) { mrow[r] = -1e30f; lrow[r] = 0.f; }

    // K staging: 512 chunks, thread owns chunk t. row = t>>3, swizzled col.
    const int kr0 = t >> 3;
    const int kc0 = ((t & 7) ^ (kr0 & 7)) * 8;
    // V staging: thread owns column d = t&63, kv rows (t>>6)*8 .. +7
    const int vd = t & 63, vk = (t >> 6) * 8;

    for (int tt = 0; tt < ntMax; tt++) {
        const int kv0 = tt * 64;
        __syncthreads();   // previous tile's LDS reads complete
        glds16(&qkv[((size_t)(b * SEQ + kv0 + kr0)) * 2304 + 768 + h * HS + kc0], &Ks[wid * 512]);
        ushort8 v8;
#pragma unroll
        for (int i = 0; i < 8; i++)
            v8[i] = qkv[((size_t)(b * SEQ + kv0 + vk + i)) * 2304 + 1536 + h * HS + vd];
        *(ushort8*)&Vt[vd * 88 + vk] = v8;
        __syncthreads();   // staging visible (drains vmcnt + lgkmcnt)

        if (tt < ntSelf)
            attn_tile(Ks, Vt, &Ps[wid][0], qf, y, mrow, lrow, q0w, kv0, tt == ntSelf - 1, lane);
    }

    // ---- write out ----
#pragma unroll
    for (int dt = 0; dt < 4; dt++)
#pragma unroll
        for (int r = 0; r < 4; r++) {
            int col = h * HS + dt * 16 + rrow;
            yb[((size_t)(b * SEQ + q0w + g * 4 + r)) * N_EMBD + col] = f2bf(y[dt][r] / lrow[r]);
        }
}

// ---------------------------------------------------------------------------
// Orchestration
// ---------------------------------------------------------------------------
extern "C" void kernel_launch(void* const* d_in, const int* in_sizes, int n_in,
                              void* d_out, int out_size, void* d_ws, size_t ws_size,
                              hipStream_t stream) {
    const float* x        = (const float*)d_in[0];
    const float* ln1_g    = (const float*)d_in[1];
    const float* ln1_b    = (const float*)d_in[2];
    const float* w_attn   = (const float*)d_in[3];
    const float* b_attn   = (const float*)d_in[4];
    const float* w_proj   = (const float*)d_in[5];
    const float* b_proj   = (const float*)d_in[6];
    const float* ln2_g    = (const float*)d_in[7];
    const float* ln2_b    = (const float*)d_in[8];
    const float* w_fc     = (const float*)d_in[9];
    const float* b_fc     = (const float*)d_in[10];
    const float* w_fcp    = (const float*)d_in[11];
    const float* b_fcp    = (const float*)d_in[12];
    float* out = (float*)d_out;

    // workspace carve (ushort elements)
    unsigned short* ws = (unsigned short*)d_ws;
    unsigned short* wT_attn = ws;                          // 2304*768
    unsigned short* wT_proj = wT_attn + 2304 * 768;        // 768*768
    unsigned short* wT_fc   = wT_proj + 768 * 768;         // 3072*768
    unsigned short* wT_fcp  = wT_fc   + 3072 * 768;        // 768*3072
    unsigned short* xb      = wT_fcp  + 768 * 3072;        // 8192*768 (ln1 out, later ln2 out)
    unsigned short* qkv     = xb      + (size_t)MROWS * 768;   // 8192*2304
    unsigned short* yb      = qkv     + (size_t)MROWS * 2304;  // 8192*768 (attn out)
    unsigned short* act     = qkv;    // 8192*3072 overlays qkv+yb (both dead by then)
    float* x2 = (float*)(yb + (size_t)MROWS * 768);        // 8192*768 fp32

    dim3 tb(32, 8);
    // weight transposes (fp32 [K,N] -> bf16 [N,K])
    tcast_kernel<<<dim3(2304 / 32, 768 / 32), tb, 0, stream>>>(w_attn, wT_attn, 768, 2304);
    tcast_kernel<<<dim3(768 / 32, 768 / 32),  tb, 0, stream>>>(w_proj, wT_proj, 768, 768);
    tcast_kernel<<<dim3(3072 / 32, 768 / 32), tb, 0, stream>>>(w_fc,   wT_fc,   768, 3072);
    tcast_kernel<<<dim3(768 / 32, 3072 / 32), tb, 0, stream>>>(w_fcp,  wT_fcp,  3072, 768);

    // ln1
    ln_kernel<<<MROWS, 256, 0, stream>>>(x, ln1_g, ln1_b, xb);
    // qkv = ln1(x) @ w_attn + b_attn
    gemm_bt_kernel<0, 4><<<dim3(2304 / 128, MROWS / 128), 256, 0, stream>>>(
        xb, wT_attn, b_attn, nullptr, nullptr, qkv, MROWS, 2304, 768);
    // attention (paired q-tiles, 8 waves)
    attn_kernel<<<dim3(8, 96), 512, 0, stream>>>(qkv, yb);
    // x2 = attn_y @ w_proj + b_proj + x     (N=768: 64x128 tile -> 768 blocks)
    gemm_bt_kernel<2, 2><<<dim3(768 / 128, MROWS / 64), 256, 0, stream>>>(
        yb, wT_proj, b_proj, x, x2, nullptr, MROWS, 768, 768);
    // ln2
    ln_kernel<<<MROWS, 256, 0, stream>>>(x2, ln2_g, ln2_b, xb);
    // act = gelu(h2 @ w_fc + b_fc)
    gemm_bt_kernel<1, 4><<<dim3(3072 / 128, MROWS / 128), 256, 0, stream>>>(
        xb, wT_fc, b_fc, nullptr, nullptr, act, MROWS, 3072, 768);
    // out = act @ w_fc_proj + b_fc_proj + x2
    gemm_bt_kernel<2, 2><<<dim3(768 / 128, MROWS / 64), 256, 0, stream>>>(
        act, wT_fcp, b_fcp, x2, out, nullptr, MROWS, 768, 3072);
}